// Round 6
// baseline (251.604 us; speedup 1.0000x reference)
//
#include <hip/hip_runtime.h>
#include <hip/hip_bf16.h>
#include <stdint.h>

#define B_SZ 8192
#define D_SZ 512
#define H_SZ 512
#define KC 1024       // concatenated K (x | hidden)
#define NPRE 2560     // Wall rows: t1,t2,i,g,o each 512

typedef __attribute__((ext_vector_type(8))) __bf16 bf16x8;
typedef __attribute__((ext_vector_type(4))) float f32x4;

__device__ __forceinline__ unsigned short f2bf(float f) {
  unsigned u = __builtin_bit_cast(unsigned, f);
  u += 0x7FFFu + ((u >> 16) & 1u);   // RNE (inputs finite)
  return (unsigned short)(u >> 16);
}
__device__ __forceinline__ float bf2f(unsigned short h) {
  unsigned u = ((unsigned)h) << 16;
  return __builtin_bit_cast(float, u);
}
// fast sigmoid/tanh: v_exp_f32 + v_rcp_f32 (|err| ~1e-6 rel, fine vs 7.5e-2 threshold)
__device__ __forceinline__ float sigf(float x) {
  return __builtin_amdgcn_rcpf(1.0f + __expf(-x));
}
__device__ __forceinline__ float tanh_fast(float x) {
  float e = __expf(-2.0f * x);
  return (1.0f - e) * __builtin_amdgcn_rcpf(1.0f + e);
}

// async 16B global->LDS (wave-uniform LDS base + lane*16; global addr per-lane)
__device__ __forceinline__ void async_ld16(const unsigned short* g, unsigned short* l) {
  __builtin_amdgcn_global_load_lds(
      (const __attribute__((address_space(1))) unsigned int*)g,
      (__attribute__((address_space(3))) unsigned int*)l, 16, 0, 0);
}

// ---------------- pack kernel (x|h concat cast + weight concat cast) ----------------
struct WSrcs { const float* wx[5]; const float* wh[3]; const float* wco; };

__global__ void pack_all(const float* __restrict__ x, const float* __restrict__ h, WSrcs ws,
                         unsigned short* __restrict__ Ab, unsigned short* __restrict__ Wall,
                         unsigned short* __restrict__ Wcob) {
  int i = (blockIdx.x * 256 + threadIdx.x) * 4;
  const int XH = B_SZ * KC;
  const float* s;
  unsigned short* d;
  if (i < XH) {
    int b = i >> 10, c = i & 1023;
    s = (c < 512) ? (x + (size_t)b * 512 + c) : (h + (size_t)b * 512 + (c - 512));
    d = Ab + i;
  } else if (i < XH + NPRE * KC) {
    int j = i - XH;
    int row = j >> 10, c = j & 1023;
    int gate = row >> 9, r = row & 511;
    d = Wall + j;
    if (c < 512) {
      s = ws.wx[gate] + (size_t)r * 512 + c;
    } else if (gate >= 2) {
      s = ws.wh[gate - 2] + (size_t)r * 512 + (c - 512);
    } else {
      return;   // t1/t2 hidden half: never read (those waves stop at kt=8)
    }
  } else {
    int j = i - XH - NPRE * KC;
    s = ws.wco + j;
    d = Wcob + j;
  }
  float4 v = *(const float4*)s;
  ushort4 o; o.x = f2bf(v.x); o.y = f2bf(v.y); o.z = f2bf(v.z); o.w = f2bf(v.w);
  *(ushort4*)d = o;
}

// ---------------- fused t1/t2/i/g/o GEMM + full gate epilogue ----------------
// Block: 640 threads = 10 waves = 2 m-halves x 5 slots (t1,t2,i,g,o), each 64x64.
// t1/t2 slots run kt<8 only (weights structurally zero beyond K=512 -> no waste).
// Grid: x = 8 (64-col h tiles), y = 64 (128-row m tiles) -> 512 blocks.
// Epilogue: two passes (per m-half): 5 acc tiles -> LDS bf16 -> gate math in-block.
__global__ __launch_bounds__(640, 2) void igo_gate(
    const unsigned short* __restrict__ A, const unsigned short* __restrict__ Wall,
    const float* __restrict__ delta_t, const float* __restrict__ cell_s,
    const float* __restrict__ bii, const float* __restrict__ bhi,
    const float* __restrict__ big, const float* __restrict__ bhg,
    const float* __restrict__ bio, const float* __restrict__ bho,
    const float* __restrict__ Wto, const float* __restrict__ bto,
    const float* __restrict__ bco,
    const float* __restrict__ bit1, const float* __restrict__ Wtt1,
    const float* __restrict__ bit2, const float* __restrict__ Wtt2,
    float* __restrict__ out_cm, unsigned short* __restrict__ cmt_b,
    unsigned short* __restrict__ ao_b) {
  // staging: 7 tiles x 512 chunks x 16 B = 56 KB; epilogue reuses 40 KB of it
  __shared__ __align__(16) unsigned short sBuf[28672];
  const int tid  = threadIdx.x;
  const int wave = tid >> 6, lane = tid & 63;
  const int ln15 = lane & 15, kq = lane >> 4;
  const int mh   = wave / 5, slot = wave % 5;   // slot: 0=t1,1=t2,2=i,3=g,4=o
  const long bm  = (long)blockIdx.y * 128;
  const int  bn64 = blockIdx.x * 64;

  f32x4 acc[4][4];
#pragma unroll
  for (int i = 0; i < 4; ++i)
#pragma unroll
    for (int j = 0; j < 4; ++j) acc[i][j] = (f32x4){0.f, 0.f, 0.f, 0.f};

  const int swb = ln15 & 7;
  bf16x8* chunks = (bf16x8*)sBuf;

  for (int kt = 0; kt < 16; ++kt) {
    const int k0 = kt << 6;
    __syncthreads();
    // stage: kt<8 -> 7 tiles (A mh0/mh1 + W t1,t2,i,g,o); kt>=8 -> 5 tiles (A + W i,g,o)
    const int cnt = (kt < 8) ? 3584 : 2560;
    for (int idx = tid; idx < cnt; idx += 640) {   // wave-uniform 64-chunk groups
      int t_lin = idx >> 9;
      int f     = idx & 511;
      int tile  = (kt < 8) ? t_lin : (t_lin < 2 ? t_lin : t_lin + 2);
      int row = f >> 3;
      int col = ((f & 7) ^ (row & 7)) << 3;        // XOR swizzle (conflict-free reads)
      const unsigned short* src;
      if (tile < 2) src = A    + (size_t)(bm + tile * 64 + row) * KC + k0 + col;
      else          src = Wall + (size_t)((tile - 2) * 512 + bn64 + row) * KC + k0 + col;
      async_ld16(src, sBuf + (size_t)(tile * 512 + f) * 8);
    }
    __syncthreads();
    if (kt < 8 || slot >= 2) {   // wave-uniform: t1/t2 waves idle for kt>=8
#pragma unroll
      for (int ko = 0; ko < 2; ++ko) {
        const int q = (ko * 4 + kq) ^ swb;
        bf16x8 af[4], wf[4];
#pragma unroll
        for (int t = 0; t < 4; ++t)
          af[t] = chunks[mh * 512 + (t * 16 + ln15) * 8 + q];
#pragma unroll
        for (int t = 0; t < 4; ++t)
          wf[t] = chunks[(2 + slot) * 512 + (t * 16 + ln15) * 8 + q];
#pragma unroll
        for (int i = 0; i < 4; ++i)
#pragma unroll
          for (int j = 0; j < 4; ++j)
            acc[i][j] = __builtin_amdgcn_mfma_f32_16x16x32_bf16(af[i], wf[j], acc[i][j], 0, 0, 0);
      }
    }
  }

  // ---- two-pass epilogue: per m-half, exchange 5 tiles via LDS, then gate math ----
  for (int mh_e = 0; mh_e < 2; ++mh_e) {
    __syncthreads();   // staging/compute or previous pass reads done
    if (mh == mh_e) {
#pragma unroll
      for (int i = 0; i < 4; ++i)
#pragma unroll
        for (int j = 0; j < 4; ++j)
#pragma unroll
          for (int r = 0; r < 4; ++r) {
            int row = i * 16 + kq * 4 + r;
            int col = j * 16 + ln15;
            sBuf[(size_t)slot * 4096 + row * 64 + col] = f2bf(acc[i][j][r]);
          }
    }
    __syncthreads();
    for (int v = tid; v < 1024; v += 640) {      // 64 rows x 16 vec4
      int row = v >> 4;
      int c4  = (v & 15) << 2;
      long b  = bm + mh_e * 64 + row;
      int  h  = bn64 + c4;
      int  lo = row * 64 + c4;
      ushort4 ut1 = *(const ushort4*)(sBuf + 0 * 4096 + lo);
      ushort4 ut2 = *(const ushort4*)(sBuf + 1 * 4096 + lo);
      ushort4 uai = *(const ushort4*)(sBuf + 2 * 4096 + lo);
      ushort4 uag = *(const ushort4*)(sBuf + 3 * 4096 + lo);
      ushort4 uao = *(const ushort4*)(sBuf + 4 * 4096 + lo);
      float4 cs   = *(const float4*)(cell_s + (size_t)b * 512 + h);
      float4 vbii = *(const float4*)(bii + h), vbhi = *(const float4*)(bhi + h);
      float4 vbig = *(const float4*)(big + h), vbhg = *(const float4*)(bhg + h);
      float4 vbio = *(const float4*)(bio + h), vbho = *(const float4*)(bho + h);
      float4 vWto = *(const float4*)(Wto + h), vbto = *(const float4*)(bto + h);
      float4 vbco = *(const float4*)(bco + h);
      float4 vbt1 = *(const float4*)(bit1 + h), vwt1 = *(const float4*)(Wtt1 + h);
      float4 vbt2 = *(const float4*)(bit2 + h), vwt2 = *(const float4*)(Wtt2 + h);
      float dtb   = delta_t[b];

      float4 ocm; ushort4 ocmt, oao;
#pragma unroll
      for (int l = 0; l < 4; ++l) {
        float t1 = sigf(bf2f(((const unsigned short*)&ut1)[l]) + ((const float*)&vbt1)[l]
                        + sigf(dtb * ((const float*)&vwt1)[l]));
        float t2 = sigf(bf2f(((const unsigned short*)&ut2)[l]) + ((const float*)&vbt2)[l]
                        + sigf(dtb * ((const float*)&vwt2)[l]));
        float ai = bf2f(((const unsigned short*)&uai)[l]) + ((const float*)&vbii)[l] + ((const float*)&vbhi)[l];
        float ag = bf2f(((const unsigned short*)&uag)[l]) + ((const float*)&vbig)[l] + ((const float*)&vbhg)[l];
        float ao = bf2f(((const unsigned short*)&uao)[l]) + ((const float*)&vbio)[l] + ((const float*)&vbho)[l]
                 + dtb * ((const float*)&vWto)[l] + ((const float*)&vbto)[l] + ((const float*)&vbco)[l];
        float im = sigf(ai);
        float g  = tanh_fast(ag);
        float csl = ((const float*)&cs)[l];
        float it1 = im * t1;
        float cmt = (1.f - it1) * csl + it1 * g;
        float cm  = (1.f - im) * csl + im * t2 * g;
        ((float*)&ocm)[l] = cm;
        ((unsigned short*)&ocmt)[l] = f2bf(cmt);
        ((unsigned short*)&oao)[l]  = f2bf(ao);
      }
      *(float4*)(out_cm + (size_t)b * 512 + h) = ocm;
      *(ushort4*)(cmt_b + (size_t)b * 512 + h) = ocmt;
      *(ushort4*)(ao_b  + (size_t)b * 512 + h) = oao;
    }
  }
}

// ---------------- GEMM3 with om/hm epilogue (R2-proven config, K=512) ----------------
__global__ __launch_bounds__(256, 2) void gemm_out(
    const unsigned short* __restrict__ A /*cmt_b BxH*/, const unsigned short* __restrict__ W /*Wco*/,
    const unsigned short* __restrict__ AO, float* __restrict__ out_hm) {
  __shared__ bf16x8 sA[128 * 8];
  __shared__ bf16x8 sW[128 * 8];
  const int tid  = threadIdx.x;
  const int wave = tid >> 6, lane = tid & 63;
  const int ln15 = lane & 15, kq = lane >> 4;
  const int wr = wave >> 1, wc = wave & 1;
  const long bm = (long)blockIdx.y * 128;
  const long bn = (long)blockIdx.x * 128;
  const int swb = ln15 & 7;

  f32x4 acc[4][4];
#pragma unroll
  for (int i = 0; i < 4; ++i)
#pragma unroll
    for (int j = 0; j < 4; ++j) acc[i][j] = (f32x4){0.f, 0.f, 0.f, 0.f};

  for (int kt = 0; kt < 8; ++kt) {    // K=512
    const int k0 = kt << 6;
    __syncthreads();
#pragma unroll
    for (int it = 0; it < 4; ++it) {
      int f   = it * 256 + tid;
      int row = f >> 3;
      int col = ((f & 7) ^ (row & 7)) << 3;
      int ldsc = it * 256 + wave * 64;
      async_ld16(A + (size_t)(bm + row) * H_SZ + k0 + col, (unsigned short*)sA + (size_t)ldsc * 8);
      async_ld16(W + (size_t)(bn + row) * H_SZ + k0 + col, (unsigned short*)sW + (size_t)ldsc * 8);
    }
    __syncthreads();
#pragma unroll
    for (int ko = 0; ko < 2; ++ko) {
      const int q = (ko * 4 + kq) ^ swb;
      bf16x8 af[4], wf[4];
#pragma unroll
      for (int t = 0; t < 4; ++t)
        af[t] = sA[(wr * 64 + t * 16 + ln15) * 8 + q];
#pragma unroll
      for (int t = 0; t < 4; ++t)
        wf[t] = sW[(wc * 64 + t * 16 + ln15) * 8 + q];
#pragma unroll
      for (int i = 0; i < 4; ++i)
#pragma unroll
        for (int j = 0; j < 4; ++j)
          acc[i][j] = __builtin_amdgcn_mfma_f32_16x16x32_bf16(af[i], wf[j], acc[i][j], 0, 0, 0);
    }
  }
#pragma unroll
  for (int i = 0; i < 4; ++i) {
    const long r0 = bm + wr * 64 + i * 16 + kq * 4;
#pragma unroll
    for (int j = 0; j < 4; ++j) {
      const long c = bn + wc * 64 + j * 16 + ln15;
#pragma unroll
      for (int r = 0; r < 4; ++r) {
        long row = r0 + r;
        size_t idx = (size_t)row * H_SZ + c;
        float ao  = bf2f(AO[idx]);
        float om  = sigf(ao + acc[i][j][r]);
        float cmt = bf2f(A[idx]);
        out_hm[idx] = om * tanh_fast(cmt);
      }
    }
  }
}

extern "C" void kernel_launch(void* const* d_in, const int* in_sizes, int n_in,
                              void* d_out, int out_size, void* d_ws, size_t ws_size,
                              hipStream_t stream) {
  const float* x    = (const float*)d_in[0];
  const float* dt   = (const float*)d_in[1];
  const float* hid  = (const float*)d_in[2];
  const float* cell = (const float*)d_in[3];
  const float* Wii  = (const float*)d_in[4];
  const float* bii  = (const float*)d_in[5];
  const float* Whi  = (const float*)d_in[6];
  const float* bhi  = (const float*)d_in[7];
  const float* Wig  = (const float*)d_in[8];
  const float* big  = (const float*)d_in[9];
  const float* Whg  = (const float*)d_in[10];
  const float* bhg  = (const float*)d_in[11];
  const float* Wio  = (const float*)d_in[12];
  const float* bio  = (const float*)d_in[13];
  const float* Who  = (const float*)d_in[14];
  const float* bho  = (const float*)d_in[15];
  const float* Wto  = (const float*)d_in[16];
  const float* bto  = (const float*)d_in[17];
  const float* Wco  = (const float*)d_in[18];
  const float* bco  = (const float*)d_in[19];
  const float* Wit1 = (const float*)d_in[20];
  const float* bit1 = (const float*)d_in[21];
  const float* Wtt1 = (const float*)d_in[22];
  const float* Wit2 = (const float*)d_in[23];
  const float* bit2 = (const float*)d_in[24];
  const float* Wtt2 = (const float*)d_in[25];

  char* wp = (char*)d_ws;
  unsigned short* Ab   = (unsigned short*)wp; wp += (size_t)B_SZ * KC * 2;
  unsigned short* Wall = (unsigned short*)wp; wp += (size_t)NPRE * KC * 2;
  unsigned short* Wcob = (unsigned short*)wp; wp += (size_t)H_SZ * H_SZ * 2;
  unsigned short* Cmtb = (unsigned short*)wp; wp += (size_t)B_SZ * H_SZ * 2;
  unsigned short* AOb  = (unsigned short*)wp; wp += (size_t)B_SZ * H_SZ * 2;

  float* out = (float*)d_out;

  WSrcs wsrc;
  wsrc.wx[0] = Wit1; wsrc.wx[1] = Wit2; wsrc.wx[2] = Wii; wsrc.wx[3] = Wig; wsrc.wx[4] = Wio;
  wsrc.wh[0] = Whi;  wsrc.wh[1] = Whg;  wsrc.wh[2] = Who; wsrc.wco = Wco;
  const int pack_elems = B_SZ * KC + NPRE * KC + H_SZ * H_SZ;
  pack_all<<<pack_elems / 4 / 256, 256, 0, stream>>>(x, hid, wsrc, Ab, Wall, Wcob);

  // fused t1/t2/i/g/o GEMM + gate math -> cm, cmt, ao
  igo_gate<<<dim3(8, 64), 640, 0, stream>>>(
      Ab, Wall, dt, cell, bii, bhi, big, bhg, bio, bho, Wto, bto, bco,
      bit1, Wtt1, bit2, Wtt2,
      out + (size_t)B_SZ * H_SZ, Cmtb, AOb);

  // hm = sig(ao + cmt@Wco^T) * tanh(cmt)
  gemm_out<<<dim3(4, 64), 256, 0, stream>>>(Cmtb, Wcob, AOb, out);
}

// Round 7
// 210.558 us; speedup vs baseline: 1.1949x; 1.1949x over previous
//
#include <hip/hip_runtime.h>
#include <hip/hip_bf16.h>
#include <stdint.h>

#define B_SZ 8192
#define D_SZ 512
#define H_SZ 512
#define KC 1024       // concatenated K (x | hidden)
#define NPRE 2560     // Wall rows: t1,t2,i,g,o each 512

typedef __attribute__((ext_vector_type(8))) __bf16 bf16x8;
typedef __attribute__((ext_vector_type(4))) float f32x4;

__device__ __forceinline__ unsigned short f2bf(float f) {
  unsigned u = __builtin_bit_cast(unsigned, f);
  u += 0x7FFFu + ((u >> 16) & 1u);   // RNE (inputs finite)
  return (unsigned short)(u >> 16);
}
__device__ __forceinline__ float bf2f(unsigned short h) {
  unsigned u = ((unsigned)h) << 16;
  return __builtin_bit_cast(float, u);
}
// fast sigmoid/tanh: v_exp_f32 + v_rcp_f32 (rel err ~1e-6, vs 7.5e-2 threshold)
__device__ __forceinline__ float sigf(float x) {
  return __builtin_amdgcn_rcpf(1.0f + __expf(-x));
}
__device__ __forceinline__ float tanh_fast(float x) {
  float e = __expf(-2.0f * x);
  return (1.0f - e) * __builtin_amdgcn_rcpf(1.0f + e);
}

// async 16B global->LDS (wave-uniform LDS base + lane*16; global addr per-lane)
__device__ __forceinline__ void async_ld16(const unsigned short* g, unsigned short* l) {
  __builtin_amdgcn_global_load_lds(
      (const __attribute__((address_space(1))) unsigned int*)g,
      (__attribute__((address_space(3))) unsigned int*)l, 16, 0, 0);
}

// ---------------- pack kernel (x|h concat cast + weight concat cast) ----------------
struct WSrcs { const float* wx[5]; const float* wh[3]; const float* wco; };

__global__ void pack_all(const float* __restrict__ x, const float* __restrict__ h, WSrcs ws,
                         unsigned short* __restrict__ Ab, unsigned short* __restrict__ Wall,
                         unsigned short* __restrict__ Wcob) {
  int i = (blockIdx.x * 256 + threadIdx.x) * 4;
  const int XH = B_SZ * KC;
  const float* s;
  unsigned short* d;
  if (i < XH) {
    int b = i >> 10, c = i & 1023;
    s = (c < 512) ? (x + (size_t)b * 512 + c) : (h + (size_t)b * 512 + (c - 512));
    d = Ab + i;
  } else if (i < XH + NPRE * KC) {
    int j = i - XH;
    int row = j >> 10, c = j & 1023;
    int gate = row >> 9, r = row & 511;
    d = Wall + j;
    if (c < 512) {
      s = ws.wx[gate] + (size_t)r * 512 + c;
    } else if (gate >= 2) {
      s = ws.wh[gate - 2] + (size_t)r * 512 + (c - 512);
    } else {
      return;   // t1/t2 hidden half: never read (gemm_t12 runs K=512)
    }
  } else {
    int j = i - XH - NPRE * KC;
    s = ws.wco + j;
    d = Wcob + j;
  }
  float4 v = *(const float4*)s;
  ushort4 o; o.x = f2bf(v.x); o.y = f2bf(v.y); o.z = f2bf(v.z); o.w = f2bf(v.w);
  *(ushort4*)d = o;
}

// ---------------- t1/t2 GEMM (K=512) with sigmoid epilogue ----------------
// 1-D grid of 512, XCD-swizzled: xcd=bid&7 owns m-tiles [xcd*8, xcd*8+8) x 8 n-tiles
// -> per-XCD L2 working set ~2 MB A-slice + 1 MB W.
__global__ __launch_bounds__(256, 2) void gemm_t12(
    const unsigned short* __restrict__ A, const unsigned short* __restrict__ W,
    unsigned short* __restrict__ T12,
    const float* __restrict__ bit1, const float* __restrict__ Wtt1,
    const float* __restrict__ bit2, const float* __restrict__ Wtt2,
    const float* __restrict__ delta_t) {
  __shared__ bf16x8 sA[128 * 8];
  __shared__ bf16x8 sW[128 * 8];
  const int tid  = threadIdx.x;
  const int wave = tid >> 6, lane = tid & 63;
  const int ln15 = lane & 15, kq = lane >> 4;
  const int wr = wave >> 1, wc = wave & 1;
  const int bid = blockIdx.x;
  const int xcd = bid & 7, idx = bid >> 3;
  const long bm = (long)(xcd * 8 + (idx >> 3)) * 128;
  const long bn = (long)(idx & 7) * 128;   // over the 1024 t1|t2 cols

  f32x4 acc[4][4];
#pragma unroll
  for (int i = 0; i < 4; ++i)
#pragma unroll
    for (int j = 0; j < 4; ++j) acc[i][j] = (f32x4){0.f, 0.f, 0.f, 0.f};

  const int swb = ln15 & 7;
  for (int kt = 0; kt < 8; ++kt) {     // K=512 (x half only)
    const int k0 = kt << 6;
    __syncthreads();
#pragma unroll
    for (int it = 0; it < 4; ++it) {
      int f   = it * 256 + tid;
      int row = f >> 3;
      int col = ((f & 7) ^ (row & 7)) << 3;
      int ldsc = it * 256 + wave * 64;
      async_ld16(A + (size_t)(bm + row) * KC + k0 + col, (unsigned short*)sA + (size_t)ldsc * 8);
      async_ld16(W + (size_t)(bn + row) * KC + k0 + col, (unsigned short*)sW + (size_t)ldsc * 8);
    }
    __syncthreads();
#pragma unroll
    for (int ko = 0; ko < 2; ++ko) {
      const int q = (ko * 4 + kq) ^ swb;
      bf16x8 af[4], wf[4];
#pragma unroll
      for (int t = 0; t < 4; ++t)
        af[t] = sA[(wr * 64 + t * 16 + ln15) * 8 + q];
#pragma unroll
      for (int t = 0; t < 4; ++t)
        wf[t] = sW[(wc * 64 + t * 16 + ln15) * 8 + q];
#pragma unroll
      for (int i = 0; i < 4; ++i)
#pragma unroll
        for (int j = 0; j < 4; ++j)
          acc[i][j] = __builtin_amdgcn_mfma_f32_16x16x32_bf16(af[i], wf[j], acc[i][j], 0, 0, 0);
    }
  }
  const float* bitp = (bn < 512) ? bit1 : bit2;
  const float* wttp = (bn < 512) ? Wtt1 : Wtt2;
#pragma unroll
  for (int i = 0; i < 4; ++i) {
    const long r0 = bm + wr * 64 + i * 16 + kq * 4;
#pragma unroll
    for (int j = 0; j < 4; ++j) {
      const long c = bn + wc * 64 + j * 16 + ln15;
      const int hc = (int)c & 511;
      const float bv = bitp[hc], wv = wttp[hc];
#pragma unroll
      for (int r = 0; r < 4; ++r) {
        const long row = r0 + r;
        float v = sigf(acc[i][j][r] + bv + sigf(delta_t[row] * wv));
        T12[(size_t)row * 1024 + c] = f2bf(v);
      }
    }
  }
}

// ---------------- fused i/g/o GEMM + gate epilogue (R4-proven shape) ----------------
// Block: 384 threads = 6 waves = 2 m-halves x 3 gate-slots(i,g,o), each 64x64, K=1024.
// 1-D grid of 512, XCD-swizzled like gemm_t12.
__global__ __launch_bounds__(384, 2) void igo_gate(
    const unsigned short* __restrict__ A, const unsigned short* __restrict__ Wigo,
    const unsigned short* __restrict__ T12,
    const float* __restrict__ delta_t, const float* __restrict__ cell_s,
    const float* __restrict__ bii, const float* __restrict__ bhi,
    const float* __restrict__ big, const float* __restrict__ bhg,
    const float* __restrict__ bio, const float* __restrict__ bho,
    const float* __restrict__ Wto, const float* __restrict__ bto,
    const float* __restrict__ bco,
    float* __restrict__ out_cm, unsigned short* __restrict__ cmt_b,
    unsigned short* __restrict__ ao_b) {
  // staging: 5 tiles x 512 chunks x 16B = 40 KB; epilogue: 6 tiles x 8 KB bf16 = 48 KB
  __shared__ __align__(16) unsigned short sBuf[24576];   // 48 KB
  const int tid  = threadIdx.x;
  const int wave = tid >> 6, lane = tid & 63;
  const int ln15 = lane & 15, kq = lane >> 4;
  const int mh   = wave / 3, slot = wave % 3;   // slot: 0=i,1=g,2=o
  const int bid  = blockIdx.x;
  const int xcd  = bid & 7, idx0 = bid >> 3;
  const long bm  = (long)(xcd * 8 + (idx0 >> 3)) * 128;
  const int  bn64 = (idx0 & 7) * 64;

  f32x4 acc[4][4];
#pragma unroll
  for (int i = 0; i < 4; ++i)
#pragma unroll
    for (int j = 0; j < 4; ++j) acc[i][j] = (f32x4){0.f, 0.f, 0.f, 0.f};

  const int swb = ln15 & 7;
  bf16x8* chunks = (bf16x8*)sBuf;

  for (int kt = 0; kt < 16; ++kt) {
    const int k0 = kt << 6;
    __syncthreads();
    // stage 5 tiles (A mh0, A mh1, Wi, Wg, Wo), 2560 chunks, 7 ragged iters
#pragma unroll
    for (int it = 0; it < 7; ++it) {
      int idx = it * 384 + tid;
      if (idx < 2560) {
        int t   = idx >> 9;
        int f   = idx & 511;
        int row = f >> 3;
        int col = ((f & 7) ^ (row & 7)) << 3;
        const unsigned short* src;
        if (t < 2) src = A    + (size_t)(bm + t * 64 + row) * KC + k0 + col;
        else       src = Wigo + (size_t)((t - 2) * 512 + bn64 + row) * KC + k0 + col;
        async_ld16(src, sBuf + (size_t)idx * 8);
      }
    }
    __syncthreads();
#pragma unroll
    for (int ko = 0; ko < 2; ++ko) {
      const int q = (ko * 4 + kq) ^ swb;
      bf16x8 af[4], wf[4];
#pragma unroll
      for (int t = 0; t < 4; ++t)
        af[t] = chunks[mh * 512 + (t * 16 + ln15) * 8 + q];
#pragma unroll
      for (int t = 0; t < 4; ++t)
        wf[t] = chunks[(2 + slot) * 512 + (t * 16 + ln15) * 8 + q];
#pragma unroll
      for (int i = 0; i < 4; ++i)
#pragma unroll
        for (int j = 0; j < 4; ++j)
          acc[i][j] = __builtin_amdgcn_mfma_f32_16x16x32_bf16(af[i], wf[j], acc[i][j], 0, 0, 0);
    }
  }

  // ---- exchange pre-activations via LDS (bf16) ----
  __syncthreads();
#pragma unroll
  for (int i = 0; i < 4; ++i)
#pragma unroll
    for (int j = 0; j < 4; ++j)
#pragma unroll
      for (int r = 0; r < 4; ++r) {
        int row = i * 16 + kq * 4 + r;        // 0..63 within wave tile
        int col = j * 16 + ln15;              // 0..63
        sBuf[(size_t)(mh * 3 + slot) * 4096 + row * 64 + col] = f2bf(acc[i][j][r]);
      }
  __syncthreads();

  // ---- gate math over 2 x 64 x 64 elements, 4 cols/thread ----
  for (int e4 = tid * 4; e4 < 8192; e4 += 384 * 4) {
    int emh = e4 >> 12;
    int rc  = e4 & 4095;
    int row = rc >> 6;
    int col = rc & 63;
    long b  = bm + emh * 64 + row;
    int  h  = bn64 + col;
    ushort4 uai = *(const ushort4*)(sBuf + (size_t)(emh * 3 + 0) * 4096 + row * 64 + col);
    ushort4 uag = *(const ushort4*)(sBuf + (size_t)(emh * 3 + 1) * 4096 + row * 64 + col);
    ushort4 uao = *(const ushort4*)(sBuf + (size_t)(emh * 3 + 2) * 4096 + row * 64 + col);
    ushort4 ut1 = *(const ushort4*)(T12 + (size_t)b * 1024 + h);
    ushort4 ut2 = *(const ushort4*)(T12 + (size_t)b * 1024 + 512 + h);
    float4 cs   = *(const float4*)(cell_s + (size_t)b * 512 + h);
    float4 vbii = *(const float4*)(bii + h), vbhi = *(const float4*)(bhi + h);
    float4 vbig = *(const float4*)(big + h), vbhg = *(const float4*)(bhg + h);
    float4 vbio = *(const float4*)(bio + h), vbho = *(const float4*)(bho + h);
    float4 vWto = *(const float4*)(Wto + h), vbto = *(const float4*)(bto + h);
    float4 vbco = *(const float4*)(bco + h);
    float dtb   = delta_t[b];

    float4 ocm; ushort4 ocmt, oao;
#pragma unroll
    for (int l = 0; l < 4; ++l) {
      float ai = bf2f(((const unsigned short*)&uai)[l]) + ((const float*)&vbii)[l] + ((const float*)&vbhi)[l];
      float ag = bf2f(((const unsigned short*)&uag)[l]) + ((const float*)&vbig)[l] + ((const float*)&vbhg)[l];
      float ao = bf2f(((const unsigned short*)&uao)[l]) + ((const float*)&vbio)[l] + ((const float*)&vbho)[l]
               + dtb * ((const float*)&vWto)[l] + ((const float*)&vbto)[l] + ((const float*)&vbco)[l];
      float t1 = bf2f(((const unsigned short*)&ut1)[l]);
      float t2 = bf2f(((const unsigned short*)&ut2)[l]);
      float im = sigf(ai);
      float g  = tanh_fast(ag);
      float csl = ((const float*)&cs)[l];
      float it1 = im * t1;
      float cmt = (1.f - it1) * csl + it1 * g;
      float cm  = (1.f - im) * csl + im * t2 * g;
      ((float*)&ocm)[l] = cm;
      ((unsigned short*)&ocmt)[l] = f2bf(cmt);
      ((unsigned short*)&oao)[l]  = f2bf(ao);
    }
    *(float4*)(out_cm + (size_t)b * 512 + h) = ocm;
    *(ushort4*)(cmt_b + (size_t)b * 512 + h) = ocmt;
    *(ushort4*)(ao_b  + (size_t)b * 512 + h) = oao;
  }
}

// ---------------- GEMM3 with om/hm epilogue (K=512, XCD-swizzled 1-D grid of 256) ----------------
__global__ __launch_bounds__(256, 2) void gemm_out(
    const unsigned short* __restrict__ A /*cmt_b BxH*/, const unsigned short* __restrict__ W /*Wco*/,
    const unsigned short* __restrict__ AO, float* __restrict__ out_hm) {
  __shared__ bf16x8 sA[128 * 8];
  __shared__ bf16x8 sW[128 * 8];
  const int tid  = threadIdx.x;
  const int wave = tid >> 6, lane = tid & 63;
  const int ln15 = lane & 15, kq = lane >> 4;
  const int wr = wave >> 1, wc = wave & 1;
  const int bid = blockIdx.x;
  const int xcd = bid & 7, idx = bid >> 3;        // idx in [0,32)
  const long bm = (long)(xcd * 8 + (idx >> 2)) * 128;
  const long bn = (long)(idx & 3) * 128;
  const int swb = ln15 & 7;

  f32x4 acc[4][4];
#pragma unroll
  for (int i = 0; i < 4; ++i)
#pragma unroll
    for (int j = 0; j < 4; ++j) acc[i][j] = (f32x4){0.f, 0.f, 0.f, 0.f};

  for (int kt = 0; kt < 8; ++kt) {    // K=512
    const int k0 = kt << 6;
    __syncthreads();
#pragma unroll
    for (int it = 0; it < 4; ++it) {
      int f   = it * 256 + tid;
      int row = f >> 3;
      int col = ((f & 7) ^ (row & 7)) << 3;
      int ldsc = it * 256 + wave * 64;
      async_ld16(A + (size_t)(bm + row) * H_SZ + k0 + col, (unsigned short*)sA + (size_t)ldsc * 8);
      async_ld16(W + (size_t)(bn + row) * H_SZ + k0 + col, (unsigned short*)sW + (size_t)ldsc * 8);
    }
    __syncthreads();
#pragma unroll
    for (int ko = 0; ko < 2; ++ko) {
      const int q = (ko * 4 + kq) ^ swb;
      bf16x8 af[4], wf[4];
#pragma unroll
      for (int t = 0; t < 4; ++t)
        af[t] = sA[(wr * 64 + t * 16 + ln15) * 8 + q];
#pragma unroll
      for (int t = 0; t < 4; ++t)
        wf[t] = sW[(wc * 64 + t * 16 + ln15) * 8 + q];
#pragma unroll
      for (int i = 0; i < 4; ++i)
#pragma unroll
        for (int j = 0; j < 4; ++j)
          acc[i][j] = __builtin_amdgcn_mfma_f32_16x16x32_bf16(af[i], wf[j], acc[i][j], 0, 0, 0);
    }
  }
#pragma unroll
  for (int i = 0; i < 4; ++i) {
    const long r0 = bm + wr * 64 + i * 16 + kq * 4;
#pragma unroll
    for (int j = 0; j < 4; ++j) {
      const long c = bn + wc * 64 + j * 16 + ln15;
#pragma unroll
      for (int r = 0; r < 4; ++r) {
        long row = r0 + r;
        size_t idx2 = (size_t)row * H_SZ + c;
        float ao  = bf2f(AO[idx2]);
        float om  = sigf(ao + acc[i][j][r]);
        float cmt = bf2f(A[idx2]);
        out_hm[idx2] = om * tanh_fast(cmt);
      }
    }
  }
}

extern "C" void kernel_launch(void* const* d_in, const int* in_sizes, int n_in,
                              void* d_out, int out_size, void* d_ws, size_t ws_size,
                              hipStream_t stream) {
  const float* x    = (const float*)d_in[0];
  const float* dt   = (const float*)d_in[1];
  const float* hid  = (const float*)d_in[2];
  const float* cell = (const float*)d_in[3];
  const float* Wii  = (const float*)d_in[4];
  const float* bii  = (const float*)d_in[5];
  const float* Whi  = (const float*)d_in[6];
  const float* bhi  = (const float*)d_in[7];
  const float* Wig  = (const float*)d_in[8];
  const float* big  = (const float*)d_in[9];
  const float* Whg  = (const float*)d_in[10];
  const float* bhg  = (const float*)d_in[11];
  const float* Wio  = (const float*)d_in[12];
  const float* bio  = (const float*)d_in[13];
  const float* Who  = (const float*)d_in[14];
  const float* bho  = (const float*)d_in[15];
  const float* Wto  = (const float*)d_in[16];
  const float* bto  = (const float*)d_in[17];
  const float* Wco  = (const float*)d_in[18];
  const float* bco  = (const float*)d_in[19];
  const float* Wit1 = (const float*)d_in[20];
  const float* bit1 = (const float*)d_in[21];
  const float* Wtt1 = (const float*)d_in[22];
  const float* Wit2 = (const float*)d_in[23];
  const float* bit2 = (const float*)d_in[24];
  const float* Wtt2 = (const float*)d_in[25];

  char* wp = (char*)d_ws;
  unsigned short* Ab   = (unsigned short*)wp; wp += (size_t)B_SZ * KC * 2;
  unsigned short* Wall = (unsigned short*)wp; wp += (size_t)NPRE * KC * 2;
  unsigned short* Wcob = (unsigned short*)wp; wp += (size_t)H_SZ * H_SZ * 2;
  unsigned short* T12  = (unsigned short*)wp; wp += (size_t)B_SZ * 1024 * 2;
  unsigned short* Cmtb = (unsigned short*)wp; wp += (size_t)B_SZ * H_SZ * 2;
  unsigned short* AOb  = (unsigned short*)wp; wp += (size_t)B_SZ * H_SZ * 2;

  float* out = (float*)d_out;

  WSrcs wsrc;
  wsrc.wx[0] = Wit1; wsrc.wx[1] = Wit2; wsrc.wx[2] = Wii; wsrc.wx[3] = Wig; wsrc.wx[4] = Wio;
  wsrc.wh[0] = Whi;  wsrc.wh[1] = Whg;  wsrc.wh[2] = Who; wsrc.wco = Wco;
  const int pack_elems = B_SZ * KC + NPRE * KC + H_SZ * H_SZ;
  pack_all<<<pack_elems / 4 / 256, 256, 0, stream>>>(x, hid, wsrc, Ab, Wall, Wcob);

  // t1,t2 (post-sigmoid); K=512, XCD-swizzled grid
  gemm_t12<<<512, 256, 0, stream>>>(Ab, Wall, T12, bit1, Wtt1, bit2, Wtt2, dt);

  // fused i/g/o GEMM (K=1024) + gate math -> cm, cmt, ao; XCD-swizzled grid
  const unsigned short* Wigo = Wall + (size_t)1024 * KC;
  igo_gate<<<512, 384, 0, stream>>>(
      Ab, Wigo, T12, dt, cell, bii, bhi, big, bhg, bio, bho, Wto, bto, bco,
      out + (size_t)B_SZ * H_SZ, Cmtb, AOb);

  // hm = sig(ao + cmt@Wco^T) * tanh(cmt); XCD-swizzled grid
  gemm_out<<<256, 256, 0, stream>>>(Cmtb, Wcob, AOb, out);
}